// Round 1
// baseline (208.890 us; speedup 1.0000x reference)
//
#include <hip/hip_runtime.h>
#include <hip/hip_bf16.h>
#include <math.h>

// CoSent clustering loss on MI355X.
// Pipeline: normalize -> bf16 MFMA GEMM tiles of S with fused exp/mask/row-reduce
//           -> per-row a,b atomics -> finalize (segment sum + log).

typedef __bf16 bf16;
typedef __attribute__((ext_vector_type(8))) __bf16 bf16x8;
typedef __attribute__((ext_vector_type(4))) float f32x4;

#define N_EMB 8192
#define D_EMB 256
#define NUM_LABELS 128

// ---------------------------------------------------------------- normalize
__global__ __launch_bounds__(256) void normalize_kernel(const float* __restrict__ emb,
                                                        bf16* __restrict__ e16,
                                                        float* __restrict__ ga,
                                                        float* __restrict__ gb) {
    const int row = blockIdx.x;
    const int tid = threadIdx.x;            // D_EMB == 256 threads, 1 elem each
    float x = emb[row * D_EMB + tid];
    float ss = x * x;
    #pragma unroll
    for (int off = 32; off >= 1; off >>= 1) ss += __shfl_xor(ss, off);
    __shared__ float wsum[4];
    if ((tid & 63) == 0) wsum[tid >> 6] = ss;
    __syncthreads();
    const float tot = wsum[0] + wsum[1] + wsum[2] + wsum[3];
    const float norm = fmaxf(sqrtf(tot), 1e-12f);
    e16[row * D_EMB + tid] = (bf16)(x / norm);
    if (tid == 0) { ga[row] = 0.0f; gb[row] = 0.0f; }   // zero accumulators
}

// ------------------------------------------------------- async global->LDS
__device__ __forceinline__ void gload_lds16(const bf16* gsrc, bf16* ldst) {
    __builtin_amdgcn_global_load_lds(
        (const __attribute__((address_space(1))) void*)gsrc,
        (__attribute__((address_space(3))) void*)ldst, 16, 0, 0);
}

// ----------------------------------------------------------------- main GEMM
// Tile 128x128, BK=32, 4 waves (2x2), each wave -> 64x64 output (4x4 frags of
// 16x16x32 MFMA). LDS layout per tile: [kc=BK/8][row=128][8 bf16] — linear in
// the global_load_lds lane order AND ~conflict-free for ds_read_b128 frags.
__global__ __launch_bounds__(256, 2) void cosent_main(const bf16* __restrict__ e,
                                                      const int* __restrict__ labels,
                                                      const float* __restrict__ scale,
                                                      float* __restrict__ ga,
                                                      float* __restrict__ gb) {
    __shared__ bf16 bufA[2][128 * 32];
    __shared__ bf16 bufB[2][128 * 32];
    __shared__ int labR[128], labC[128];

    const int tid = threadIdx.x;
    const int lane = tid & 63;
    const int wid = tid >> 6;
    const int rowBase = blockIdx.y * 128;
    const int colBase = blockIdx.x * 128;

    if (tid < 128) labR[tid] = labels[rowBase + tid];
    else           labC[tid - 128] = labels[colBase + (tid - 128)];

    const int wm = wid >> 1, wn = wid & 1;

    f32x4 acc[4][4];
    #pragma unroll
    for (int i = 0; i < 4; ++i)
        #pragma unroll
        for (int j = 0; j < 4; ++j) acc[i][j] = (f32x4){0.f, 0.f, 0.f, 0.f};

    // stage one K-slab (A rows + B cols) into buffer b, k-offset k0.
    // chunk q = (i*4+wid)*64 + lane ; kc = q>>7 ; r = q&127 ;
    // LDS linear offset = q*16B  == [kc][r][8] layout.
    auto stage = [&](int b, int k0) {
        #pragma unroll
        for (int i = 0; i < 2; ++i) {
            const int qb = (i * 4 + wid) * 64;     // wave-uniform chunk base
            const int q = qb + lane;
            const int kc = q >> 7, r = q & 127;
            gload_lds16(e + (size_t)(rowBase + r) * D_EMB + k0 + kc * 8, &bufA[b][qb * 8]);
            gload_lds16(e + (size_t)(colBase + r) * D_EMB + k0 + kc * 8, &bufB[b][qb * 8]);
        }
    };

    stage(0, 0);
    __syncthreads();           // drains vmcnt

    int cur = 0;
    const int kc = lane >> 4, rr = lane & 15;
    #pragma unroll
    for (int t = 0; t < 8; ++t) {          // K = 256 = 8 * BK(32)
        if (t < 7) stage(cur ^ 1, (t + 1) * 32);
        bf16x8 af[4], bfg[4];
        #pragma unroll
        for (int mi = 0; mi < 4; ++mi)
            af[mi] = *(const bf16x8*)&bufA[cur][(kc * 128 + wm * 64 + mi * 16 + rr) * 8];
        #pragma unroll
        for (int ni = 0; ni < 4; ++ni)
            bfg[ni] = *(const bf16x8*)&bufB[cur][(kc * 128 + wn * 64 + ni * 16 + rr) * 8];
        #pragma unroll
        for (int mi = 0; mi < 4; ++mi)
            #pragma unroll
            for (int ni = 0; ni < 4; ++ni)
                acc[mi][ni] = __builtin_amdgcn_mfma_f32_16x16x32_bf16(af[mi], bfg[ni],
                                                                      acc[mi][ni], 0, 0, 0);
        __syncthreads();       // waits vmcnt(0) (stage) + lgkmcnt (ds reads)
        cur ^= 1;
    }

    // ---------------- fused epilogue: exp/mask + row reduction + atomics
    const float s = *scale;
    #pragma unroll
    for (int mi = 0; mi < 4; ++mi) {
        #pragma unroll
        for (int r = 0; r < 4; ++r) {
            const int rowL = wm * 64 + mi * 16 + (lane >> 4) * 4 + r;
            const int grow = rowBase + rowL;
            const int lr = labR[rowL];
            float asum = 0.f, bsum = 0.f;
            #pragma unroll
            for (int ni = 0; ni < 4; ++ni) {
                const int colL = wn * 64 + ni * 16 + (lane & 15);
                const int gcol = colBase + colL;
                const float val = acc[mi][ni][r] * s;
                if (grow != gcol) {
                    if (lr == labC[colL]) asum += __expf(-val);   // positive pair
                    else                  bsum += __expf(val);    // negative pair
                }
            }
            // reduce across the 16 lanes sharing this row
            #pragma unroll
            for (int off = 1; off < 16; off <<= 1) {
                asum += __shfl_xor(asum, off);
                bsum += __shfl_xor(bsum, off);
            }
            if ((lane & 15) == 0) {
                atomicAdd(&ga[grow], asum);
                atomicAdd(&gb[grow], bsum);
            }
        }
    }
}

// ----------------------------------------------------------------- finalize
__global__ __launch_bounds__(256) void finalize_kernel(const float* __restrict__ ga,
                                                       const float* __restrict__ gb,
                                                       const int* __restrict__ labels,
                                                       float* __restrict__ out) {
    __shared__ float A[NUM_LABELS], B[NUM_LABELS];
    __shared__ int cnt[NUM_LABELS];
    const int tid = threadIdx.x;
    if (tid < NUM_LABELS) { A[tid] = 0.f; B[tid] = 0.f; cnt[tid] = 0; }
    __syncthreads();
    for (int i = tid; i < N_EMB; i += 256) {
        const int l = labels[i];
        atomicAdd(&A[l], ga[i]);
        atomicAdd(&B[l], gb[i]);
        atomicAdd(&cnt[l], 1);
    }
    __syncthreads();
    float v = 0.f;
    if (tid < NUM_LABELS && cnt[tid] >= 2) v = A[tid] * B[tid];
    #pragma unroll
    for (int off = 32; off >= 1; off >>= 1) v += __shfl_xor(v, off);
    __shared__ float wsum[4];
    if ((tid & 63) == 0) wsum[tid >> 6] = v;
    __syncthreads();
    if (tid == 0) out[0] = logf(1.0f + wsum[0] + wsum[1] + wsum[2] + wsum[3]);
}

// ------------------------------------------------------------------ launcher
extern "C" void kernel_launch(void* const* d_in, const int* in_sizes, int n_in,
                              void* d_out, int out_size, void* d_ws, size_t ws_size,
                              hipStream_t stream) {
    const float* emb    = (const float*)d_in[0];
    const int*   labels = (const int*)d_in[1];
    const float* scale  = (const float*)d_in[2];
    float* out = (float*)d_out;

    bf16*  e16 = (bf16*)d_ws;
    float* ga  = (float*)((char*)d_ws + (size_t)N_EMB * D_EMB * sizeof(bf16));
    float* gb  = ga + N_EMB;

    normalize_kernel<<<N_EMB, 256, 0, stream>>>(emb, e16, ga, gb);
    dim3 grid(N_EMB / 128, N_EMB / 128);
    cosent_main<<<grid, 256, 0, stream>>>(e16, labels, scale, ga, gb);
    finalize_kernel<<<1, 256, 0, stream>>>(ga, gb, labels, out);
}

// Round 2
// 131.540 us; speedup vs baseline: 1.5880x; 1.5880x over previous
//
#include <hip/hip_runtime.h>
#include <hip/hip_bf16.h>
#include <math.h>

// CoSent clustering loss on MI355X — round 2.
// normalize -> 256x256-tile bf16 MFMA GEMM (8 waves, BK=64, dbuf) with fused
// exp/mask/row-reduce -> per-block partial stores (NO global atomics)
// -> 32-block row reduction + per-label segment partials -> 1-block finalize.

typedef __bf16 bf16;
typedef __attribute__((ext_vector_type(8))) __bf16 bf16x8;
typedef __attribute__((ext_vector_type(4))) float f32x4;

#define N_EMB 8192
#define D_EMB 256
#define NUM_LABELS 128
#define BM 256
#define BN 256
#define BK 64
#define NROWP (N_EMB / BM)   // 32
#define NCOLP (N_EMB / BN)   // 32

// ---------------------------------------------------------------- normalize
__global__ __launch_bounds__(256) void normalize_kernel(const float* __restrict__ emb,
                                                        bf16* __restrict__ e16) {
    const int row = blockIdx.x;
    const int tid = threadIdx.x;            // D_EMB == 256 threads, 1 elem each
    float x = emb[row * D_EMB + tid];
    float ss = x * x;
    #pragma unroll
    for (int off = 32; off >= 1; off >>= 1) ss += __shfl_xor(ss, off);
    __shared__ float wsum[4];
    if ((tid & 63) == 0) wsum[tid >> 6] = ss;
    __syncthreads();
    const float tot = wsum[0] + wsum[1] + wsum[2] + wsum[3];
    const float norm = fmaxf(sqrtf(tot), 1e-12f);
    e16[row * D_EMB + tid] = (bf16)(x / norm);
}

// ------------------------------------------------------- async global->LDS
__device__ __forceinline__ void gload_lds16(const bf16* gsrc, bf16* ldst) {
    __builtin_amdgcn_global_load_lds(
        (const __attribute__((address_space(1))) void*)gsrc,
        (__attribute__((address_space(3))) void*)ldst, 16, 0, 0);
}

// ----------------------------------------------------------------- main GEMM
// 256x256 tile, BK=64, 8 waves as 2(M) x 4(N): per-wave output 128x64 =
// 8x4 frags of 16x16x32 MFMA. LDS layout per K-slab: [kc=BK/8][256][8 bf16]
// (linear in global_load_lds lane order; conflict-free ds_read_b128 frags).
__global__ __launch_bounds__(512, 2) void cosent_main(const bf16* __restrict__ e,
                                                      const int* __restrict__ labels,
                                                      const float* __restrict__ scale,
                                                      float* __restrict__ wsA,
                                                      float* __restrict__ wsB) {
    __shared__ bf16 bufA[2][BM * BK];
    __shared__ bf16 bufB[2][BN * BK];
    __shared__ int labR[BM], labC[BN];
    __shared__ float sA[BM], sB[BM];

    const int tid = threadIdx.x;
    const int lane = tid & 63;
    const int wid = tid >> 6;         // 0..7
    const int wm = wid >> 2;          // 0..1  (row half, 128 rows each)
    const int wn = wid & 3;           // 0..3  (col quarter, 64 cols each)
    const int rowBase = blockIdx.y * BM;
    const int colBase = blockIdx.x * BN;

    if (tid < BM) { labR[tid] = labels[rowBase + tid]; sA[tid] = 0.f; sB[tid] = 0.f; }
    else          { labC[tid - BM] = labels[colBase + tid - BM]; }  // BM+BN == 512

    f32x4 acc[8][4];
    #pragma unroll
    for (int i = 0; i < 8; ++i)
        #pragma unroll
        for (int j = 0; j < 4; ++j) acc[i][j] = (f32x4){0.f, 0.f, 0.f, 0.f};

    // stage one K-slab (A rows + B cols) into buffer b at k-offset k0.
    // q = i*512 + tid ; kc = q>>8 ; r = q&255 ; LDS linear ofs q*16B == [kc][r][8].
    auto stage = [&](int b, int k0) {
        #pragma unroll
        for (int i = 0; i < 4; ++i) {
            const int q = i * 512 + tid;
            const int kc = q >> 8, r = q & 255;
            gload_lds16(e + (size_t)(rowBase + r) * D_EMB + k0 + kc * 8, &bufA[b][q * 8]);
        }
        #pragma unroll
        for (int i = 0; i < 4; ++i) {
            const int q = i * 512 + tid;
            const int kc = q >> 8, r = q & 255;
            gload_lds16(e + (size_t)(colBase + r) * D_EMB + k0 + kc * 8, &bufB[b][q * 8]);
        }
    };

    stage(0, 0);
    __syncthreads();

    int cur = 0;
    const int rr = lane & 15;
    #pragma unroll
    for (int t = 0; t < 4; ++t) {           // K = 256 = 4 * BK(64)
        if (t < 3) stage(cur ^ 1, (t + 1) * BK);
        #pragma unroll
        for (int k32 = 0; k32 < 2; ++k32) {
            const int kb = (k32 * 4 + (lane >> 4)) * 256;   // k-chunk row base
            bf16x8 bfr[4];
            #pragma unroll
            for (int ni = 0; ni < 4; ++ni)
                bfr[ni] = *(const bf16x8*)&bufB[cur][(kb + wn * 64 + ni * 16 + rr) * 8];
            #pragma unroll
            for (int mi = 0; mi < 8; ++mi) {
                const bf16x8 af = *(const bf16x8*)&bufA[cur][(kb + wm * 128 + mi * 16 + rr) * 8];
                #pragma unroll
                for (int ni = 0; ni < 4; ++ni)
                    acc[mi][ni] = __builtin_amdgcn_mfma_f32_16x16x32_bf16(af, bfr[ni],
                                                                          acc[mi][ni], 0, 0, 0);
            }
        }
        __syncthreads();
        cur ^= 1;
    }

    // ---------------- fused epilogue: exp/mask + 16-lane row reduce + LDS combine
    const float s = *scale;
    #pragma unroll
    for (int mi = 0; mi < 8; ++mi) {
        #pragma unroll
        for (int r = 0; r < 4; ++r) {
            const int rowL = wm * 128 + mi * 16 + (lane >> 4) * 4 + r;
            const int grow = rowBase + rowL;
            const int lr = labR[rowL];
            float asum = 0.f, bsum = 0.f;
            #pragma unroll
            for (int ni = 0; ni < 4; ++ni) {
                const int colL = wn * 64 + ni * 16 + (lane & 15);
                const int gcol = colBase + colL;
                const float val = acc[mi][ni][r] * s;
                if (grow != gcol) {
                    if (lr == labC[colL]) asum += __expf(-val);   // positive pair
                    else                  bsum += __expf(val);    // negative pair
                }
            }
            #pragma unroll
            for (int off = 1; off < 16; off <<= 1) {
                asum += __shfl_xor(asum, off);
                bsum += __shfl_xor(bsum, off);
            }
            if ((lane & 15) == 0) {           // lanes 0,16,32,48
                atomicAdd(&sA[rowL], asum);   // LDS atomics: cheap, 4-way max
                atomicAdd(&sB[rowL], bsum);
            }
        }
    }
    __syncthreads();
    if (tid < BM) {   // one plain store per (col-panel, row) — no global atomics
        wsA[(size_t)blockIdx.x * N_EMB + rowBase + tid] = sA[tid];
        wsB[(size_t)blockIdx.x * N_EMB + rowBase + tid] = sB[tid];
    }
}

// --------------------------------------------------- per-row + segment reduce
__global__ __launch_bounds__(256) void reduce_rows(const float* __restrict__ wsA,
                                                   const float* __restrict__ wsB,
                                                   const int* __restrict__ labels,
                                                   float* __restrict__ part) {
    __shared__ float A[NUM_LABELS], B[NUM_LABELS];
    __shared__ int C[NUM_LABELS];
    const int tid = threadIdx.x;
    if (tid < NUM_LABELS) { A[tid] = 0.f; B[tid] = 0.f; C[tid] = 0; }
    __syncthreads();
    const int row = blockIdx.x * 256 + tid;
    float a = 0.f, b = 0.f;
    #pragma unroll
    for (int j = 0; j < NCOLP; ++j) {
        a += wsA[(size_t)j * N_EMB + row];
        b += wsB[(size_t)j * N_EMB + row];
    }
    const int l = labels[row];
    atomicAdd(&A[l], a);
    atomicAdd(&B[l], b);
    atomicAdd(&C[l], 1);
    __syncthreads();
    if (tid < NUM_LABELS) {
        float* p = part + ((size_t)blockIdx.x * NUM_LABELS + tid) * 3;
        p[0] = A[tid]; p[1] = B[tid]; p[2] = (float)C[tid];
    }
}

// ----------------------------------------------------------------- finalize
__global__ __launch_bounds__(128) void finalize_kernel(const float* __restrict__ part,
                                                       float* __restrict__ out) {
    const int tid = threadIdx.x;   // 0..127 == label id
    float A = 0.f, B = 0.f, c = 0.f;
    #pragma unroll
    for (int blk = 0; blk < 32; ++blk) {
        const float* p = part + ((size_t)blk * NUM_LABELS + tid) * 3;
        A += p[0]; B += p[1]; c += p[2];
    }
    float v = (c >= 2.f) ? A * B : 0.f;
    #pragma unroll
    for (int off = 32; off >= 1; off >>= 1) v += __shfl_xor(v, off);
    __shared__ float w2[2];
    if ((tid & 63) == 0) w2[tid >> 6] = v;
    __syncthreads();
    if (tid == 0) out[0] = logf(1.0f + w2[0] + w2[1]);
}

// ------------------------------------------------------------------ launcher
extern "C" void kernel_launch(void* const* d_in, const int* in_sizes, int n_in,
                              void* d_out, int out_size, void* d_ws, size_t ws_size,
                              hipStream_t stream) {
    const float* emb    = (const float*)d_in[0];
    const int*   labels = (const int*)d_in[1];
    const float* scale  = (const float*)d_in[2];
    float* out = (float*)d_out;

    bf16*  e16  = (bf16*)d_ws;                                         // 4 MB
    float* wsA  = (float*)((char*)d_ws + (size_t)N_EMB * D_EMB * sizeof(bf16));
    float* wsB  = wsA + (size_t)NCOLP * N_EMB;                         // 1 MB each
    float* part = wsB + (size_t)NCOLP * N_EMB;                         // 48 KB

    normalize_kernel<<<N_EMB, 256, 0, stream>>>(emb, e16);
    dim3 grid(NCOLP, NROWP);
    cosent_main<<<grid, 512, 0, stream>>>(e16, labels, scale, wsA, wsB);
    reduce_rows<<<N_EMB / 256, 256, 0, stream>>>(wsA, wsB, labels, part);
    finalize_kernel<<<1, 128, 0, stream>>>(part, out);
}

// Round 3
// 90.752 us; speedup vs baseline: 2.3018x; 1.4495x over previous
//
#include <hip/hip_runtime.h>
#include <hip/hip_bf16.h>
#include <math.h>

// CoSent clustering loss on MI355X — round 3.
// normalize -> triangular-grid 128x128 bf16 MFMA tiles, fragments loaded
// DIRECTLY from L2 (no LDS staging, no K-loop barriers), fused exp/mask with
// DPP row-reduce + per-lane col-reduce (symmetry: each tile serves rows AND
// cols) -> packed bf16 partials -> reduce + finalize.

typedef __bf16 bf16;
typedef __attribute__((ext_vector_type(4))) __bf16 bf16x4;
typedef __attribute__((ext_vector_type(8))) __bf16 bf16x8;
typedef __attribute__((ext_vector_type(4))) float f32x4;

#define N_EMB 8192
#define D_EMB 256
#define NUM_LABELS 128
#define PAN 128
#define NPAN (N_EMB / PAN)          // 64
#define NTRI (NPAN * (NPAN + 1) / 2) // 2080

// ---- DPP helpers: reduce over the 16 lanes sharing a fragment row-group ----
template <int CTRL>
__device__ __forceinline__ float dpp_add(float x) {
    int y = __builtin_amdgcn_update_dpp(0, __builtin_bit_cast(int, x),
                                        CTRL, 0xF, 0xF, false);
    return x + __builtin_bit_cast(float, y);
}
__device__ __forceinline__ float red16(float x) {
    x = dpp_add<0xB1>(x);    // quad_perm xor1
    x = dpp_add<0x4E>(x);    // quad_perm xor2
    x = dpp_add<0x124>(x);   // row_ror:4
    x = dpp_add<0x128>(x);   // row_ror:8  -> all 16 lanes hold the sum
    return x;
}

__device__ __forceinline__ unsigned packbf(float a, float b) {
    unsigned ua = __builtin_bit_cast(unsigned, a);
    unsigned ub = __builtin_bit_cast(unsigned, b);
    ua += 0x7FFFu + ((ua >> 16) & 1u);   // RTNE to bf16
    ub += 0x7FFFu + ((ub >> 16) & 1u);
    return (ua >> 16) | (ub & 0xFFFF0000u);
}

// ---------------------------------------------------------------- normalize
// 1 wave per row, 4 rows per block.
__global__ __launch_bounds__(256) void normalize_kernel(const float* __restrict__ emb,
                                                        bf16* __restrict__ e16) {
    const int wid = threadIdx.x >> 6, lane = threadIdx.x & 63;
    const int row = blockIdx.x * 4 + wid;
    const f32x4 x = *(const f32x4*)(emb + (size_t)row * D_EMB + lane * 4);
    float ss = x[0]*x[0] + x[1]*x[1] + x[2]*x[2] + x[3]*x[3];
    #pragma unroll
    for (int off = 32; off >= 1; off >>= 1) ss += __shfl_xor(ss, off);
    const float r = 1.0f / fmaxf(sqrtf(ss), 1e-12f);
    bf16x4 o;
    #pragma unroll
    for (int i = 0; i < 4; ++i) o[i] = (bf16)(x[i] * r);
    *(bf16x4*)(e16 + (size_t)row * D_EMB + lane * 4) = o;
}

// ----------------------------------------------------------------- main GEMM
// Triangular grid over 64x64 panels of 128. Block = 4 waves (2x2), per-wave
// 64x64 output = 4x4 frags of 16x16x32. Fragments read directly from global
// (L2-resident e16); zero K-loop barriers.
__global__ __launch_bounds__(256, 4) void cosent_main(const bf16* __restrict__ e,
                                                      const int* __restrict__ labels,
                                                      const float* __restrict__ scale,
                                                      unsigned* __restrict__ wsAB) {
    __shared__ float rowsc[2][PAN][2];   // [wn][row][a,b]
    __shared__ float colsc[2][PAN][2];   // [wm][col][a,b]
    __shared__ int labR[PAN], labC[PAN];

    // triangular decode: by <= bx
    int rem = blockIdx.x, by = 0;
    while (rem >= NPAN - by) { rem -= NPAN - by; ++by; }
    const int bx = by + rem;
    const bool diag = (bx == by);
    const int rowBase = by * PAN, colBase = bx * PAN;

    const int tid = threadIdx.x, lane = tid & 63, wid = tid >> 6;
    const int wm = wid >> 1, wn = wid & 1;

    if (tid < PAN) labR[tid] = labels[rowBase + tid];
    else           labC[tid - PAN] = labels[colBase + tid - PAN];
    __syncthreads();

    // per-lane fragment base pointers (A rows / B cols; identical layout: e.e^T)
    const bf16* aB = e + (size_t)(rowBase + wm * 64 + (lane & 15)) * D_EMB + ((lane >> 4) * 8);
    const bf16* bB = e + (size_t)(colBase + wn * 64 + (lane & 15)) * D_EMB + ((lane >> 4) * 8);

    f32x4 acc[4][4];
    #pragma unroll
    for (int i = 0; i < 4; ++i)
        #pragma unroll
        for (int j = 0; j < 4; ++j) acc[i][j] = (f32x4){0.f, 0.f, 0.f, 0.f};

    #pragma unroll
    for (int t = 0; t < 8; ++t) {        // K = 256 = 8 * 32
        bf16x8 af[4], bg[4];
        #pragma unroll
        for (int i = 0; i < 4; ++i) {
            af[i] = *(const bf16x8*)(aB + (size_t)i * 16 * D_EMB + t * 32);
            bg[i] = *(const bf16x8*)(bB + (size_t)i * 16 * D_EMB + t * 32);
        }
        #pragma unroll
        for (int mi = 0; mi < 4; ++mi)
            #pragma unroll
            for (int ni = 0; ni < 4; ++ni)
                acc[mi][ni] = __builtin_amdgcn_mfma_f32_16x16x32_bf16(af[mi], bg[ni],
                                                                      acc[mi][ni], 0, 0, 0);
    }

    // ------------- fused epilogue: one exp per element, row + col partials
    const float s = *scale;
    int lc[4];
    #pragma unroll
    for (int ni = 0; ni < 4; ++ni) lc[ni] = labC[wn * 64 + ni * 16 + (lane & 15)];
    float colA[4] = {0.f, 0.f, 0.f, 0.f}, colB[4] = {0.f, 0.f, 0.f, 0.f};

    #pragma unroll
    for (int mi = 0; mi < 4; ++mi) {
        #pragma unroll
        for (int r = 0; r < 4; ++r) {
            const int rowL = wm * 64 + mi * 16 + (lane >> 4) * 4 + r;
            const int lr = labR[rowL];
            float asum = 0.f, bsum = 0.f;
            #pragma unroll
            for (int ni = 0; ni < 4; ++ni) {
                const int colL = wn * 64 + ni * 16 + (lane & 15);
                const float val = acc[mi][ni][r] * s;
                const bool pos = (lr == lc[ni]);
                float ex = __expf(pos ? -val : val);
                if (diag && rowL == colL) ex = 0.f;   // exclude self-pairs
                if (pos) { asum += ex; colA[ni] += ex; }
                else     { bsum += ex; colB[ni] += ex; }
            }
            asum = red16(asum);
            bsum = red16(bsum);
            if ((lane & 15) == 0) { rowsc[wn][rowL][0] = asum; rowsc[wn][rowL][1] = bsum; }
        }
    }

    if (!diag) {   // col-side (transposed contribution)
        #pragma unroll
        for (int ni = 0; ni < 4; ++ni) {
            float a = colA[ni], b = colB[ni];
            a += __shfl_xor(a, 16); a += __shfl_xor(a, 32);
            b += __shfl_xor(b, 16); b += __shfl_xor(b, 32);
            if (lane < 16) {
                colsc[wm][wn * 64 + ni * 16 + lane][0] = a;
                colsc[wm][wn * 64 + ni * 16 + lane][1] = b;
            }
        }
    }
    __syncthreads();

    if (tid < PAN) {
        const float ra = rowsc[0][tid][0] + rowsc[1][tid][0];
        const float rb = rowsc[0][tid][1] + rowsc[1][tid][1];
        wsAB[(size_t)bx * N_EMB + rowBase + tid] = packbf(ra, rb);
        if (!diag) {
            const float ca = colsc[0][tid][0] + colsc[1][tid][0];
            const float cb = colsc[0][tid][1] + colsc[1][tid][1];
            wsAB[(size_t)by * N_EMB + colBase + tid] = packbf(ca, cb);
        }
    }
}

// --------------------------------------------------- per-row + segment reduce
__global__ __launch_bounds__(256) void reduce_rows(const unsigned* __restrict__ wsAB,
                                                   const int* __restrict__ labels,
                                                   float* __restrict__ part) {
    __shared__ float A[NUM_LABELS], B[NUM_LABELS];
    __shared__ int C[NUM_LABELS];
    const int tid = threadIdx.x;
    if (tid < NUM_LABELS) { A[tid] = 0.f; B[tid] = 0.f; C[tid] = 0; }
    __syncthreads();
    const int row = blockIdx.x * 256 + tid;
    float a = 0.f, b = 0.f;
    #pragma unroll
    for (int p = 0; p < NPAN; ++p) {
        const unsigned u = wsAB[(size_t)p * N_EMB + row];
        a += __builtin_bit_cast(float, u << 16);
        b += __builtin_bit_cast(float, u & 0xFFFF0000u);
    }
    const int l = labels[row];
    atomicAdd(&A[l], a);
    atomicAdd(&B[l], b);
    atomicAdd(&C[l], 1);
    __syncthreads();
    if (tid < NUM_LABELS) {
        float* p = part + ((size_t)blockIdx.x * NUM_LABELS + tid) * 3;
        p[0] = A[tid]; p[1] = B[tid]; p[2] = (float)C[tid];
    }
}

// ----------------------------------------------------------------- finalize
__global__ __launch_bounds__(128) void finalize_kernel(const float* __restrict__ part,
                                                       float* __restrict__ out) {
    const int tid = threadIdx.x;   // label id
    float A = 0.f, B = 0.f, c = 0.f;
    #pragma unroll
    for (int blk = 0; blk < 32; ++blk) {
        const float* p = part + ((size_t)blk * NUM_LABELS + tid) * 3;
        A += p[0]; B += p[1]; c += p[2];
    }
    float v = (c >= 2.f) ? A * B : 0.f;
    #pragma unroll
    for (int off = 32; off >= 1; off >>= 1) v += __shfl_xor(v, off);
    __shared__ float w2[2];
    if ((tid & 63) == 0) w2[tid >> 6] = v;
    __syncthreads();
    if (tid == 0) out[0] = logf(1.0f + w2[0] + w2[1]);
}

// ------------------------------------------------------------------ launcher
extern "C" void kernel_launch(void* const* d_in, const int* in_sizes, int n_in,
                              void* d_out, int out_size, void* d_ws, size_t ws_size,
                              hipStream_t stream) {
    const float* emb    = (const float*)d_in[0];
    const int*   labels = (const int*)d_in[1];
    const float* scale  = (const float*)d_in[2];
    float* out = (float*)d_out;

    bf16*     e16  = (bf16*)d_ws;                                     // 4 MB
    unsigned* wsAB = (unsigned*)((char*)d_ws + (size_t)N_EMB * D_EMB * sizeof(bf16)); // 2 MB
    float*    part = (float*)((char*)wsAB + (size_t)NPAN * N_EMB * sizeof(unsigned)); // 48 KB

    normalize_kernel<<<N_EMB / 4, 256, 0, stream>>>(emb, e16);
    cosent_main<<<NTRI, 256, 0, stream>>>(e16, labels, scale, wsAB);
    reduce_rows<<<N_EMB / 256, 256, 0, stream>>>(wsAB, labels, part);
    finalize_kernel<<<1, 128, 0, stream>>>(part, out);
}

// Round 4
// 72.203 us; speedup vs baseline: 2.8931x; 1.2569x over previous
//
#include <hip/hip_runtime.h>
#include <hip/hip_bf16.h>
#include <math.h>

// CoSent clustering loss on MI355X — round 4.
// normalize -> triangular 128x128 tiles; A operand hoisted fully into
// registers (32 frags, one load burst); B panel staged once into LDS
// (row-major + XOR swizzle via pre-swizzled global source); single barrier;
// barrier-free K-loop of ds_read+MFMA; fused exp/mask epilogue with DPP
// row-reduce + col-side (symmetry) -> packed bf16 partials -> reduce+finalize.

typedef __bf16 bf16;
typedef __attribute__((ext_vector_type(4))) __bf16 bf16x4;
typedef __attribute__((ext_vector_type(8))) __bf16 bf16x8;
typedef __attribute__((ext_vector_type(4))) float f32x4;

#define N_EMB 8192
#define D_EMB 256
#define NUM_LABELS 128
#define PAN 128
#define NPAN (N_EMB / PAN)           // 64
#define NTRI (NPAN * (NPAN + 1) / 2) // 2080

// ---- DPP 16-lane reduction helpers ----
template <int CTRL>
__device__ __forceinline__ float dpp_add(float x) {
    int y = __builtin_amdgcn_update_dpp(0, __builtin_bit_cast(int, x),
                                        CTRL, 0xF, 0xF, false);
    return x + __builtin_bit_cast(float, y);
}
__device__ __forceinline__ float red16(float x) {
    x = dpp_add<0xB1>(x);    // quad_perm xor1
    x = dpp_add<0x4E>(x);    // quad_perm xor2
    x = dpp_add<0x124>(x);   // row_ror:4
    x = dpp_add<0x128>(x);   // row_ror:8
    return x;
}

__device__ __forceinline__ unsigned packbf(float a, float b) {
    unsigned ua = __builtin_bit_cast(unsigned, a);
    unsigned ub = __builtin_bit_cast(unsigned, b);
    ua += 0x7FFFu + ((ua >> 16) & 1u);   // RTNE to bf16
    ub += 0x7FFFu + ((ub >> 16) & 1u);
    return (ua >> 16) | (ub & 0xFFFF0000u);
}

// ---------------------------------------------------------------- normalize
__global__ __launch_bounds__(256) void normalize_kernel(const float* __restrict__ emb,
                                                        bf16* __restrict__ e16) {
    const int wid = threadIdx.x >> 6, lane = threadIdx.x & 63;
    const int row = blockIdx.x * 4 + wid;
    const f32x4 x = *(const f32x4*)(emb + (size_t)row * D_EMB + lane * 4);
    float ss = x[0]*x[0] + x[1]*x[1] + x[2]*x[2] + x[3]*x[3];
    #pragma unroll
    for (int off = 32; off >= 1; off >>= 1) ss += __shfl_xor(ss, off);
    const float r = 1.0f / fmaxf(sqrtf(ss), 1e-12f);
    bf16x4 o;
    #pragma unroll
    for (int i = 0; i < 4; ++i) o[i] = (bf16)(x[i] * r);
    *(bf16x4*)(e16 + (size_t)row * D_EMB + lane * 4) = o;
}

// ------------------------------------------------------- async global->LDS
__device__ __forceinline__ void gload_lds16(const bf16* gsrc, bf16* ldst) {
    __builtin_amdgcn_global_load_lds(
        (const __attribute__((address_space(1))) void*)gsrc,
        (__attribute__((address_space(3))) void*)ldst, 16, 0, 0);
}

// ----------------------------------------------------------------- main GEMM
// 4 waves (2x2), per-wave 64x64 = 4x4 frags of 16x16x32.
// B LDS layout: row-major [128 cols][32 kchunks][8 bf16], chunk index XOR-
// swizzled (kc ^ (col&7)); staging uses the inverse-swizzled global source so
// the linear global_load_lds dest lands each element at its swizzled slot.
__global__ __launch_bounds__(256, 2) void cosent_main(const bf16* __restrict__ e,
                                                      const int* __restrict__ labels,
                                                      const float* __restrict__ scale,
                                                      unsigned* __restrict__ wsAB) {
    __shared__ bf16 bufB[PAN * D_EMB];      // 64 KB
    __shared__ float rowsc[2][PAN][2];
    __shared__ float colsc[2][PAN][2];
    __shared__ int labR[PAN], labC[PAN];

    // triangular decode: by <= bx
    int rem = blockIdx.x, by = 0;
    while (rem >= NPAN - by) { rem -= NPAN - by; ++by; }
    const int bx = by + rem;
    const bool diag = (bx == by);
    const int rowBase = by * PAN, colBase = bx * PAN;

    const int tid = threadIdx.x, lane = tid & 63, wid = tid >> 6;
    const int wm = wid >> 1, wn = wid & 1;
    const int rr = lane & 15, kh = lane >> 4;

    if (tid < PAN) labR[tid] = labels[rowBase + tid];
    else           labC[tid - PAN] = labels[colBase + tid - PAN];

    // ---- stage B panel (once, full K) with pre-swizzled source ----
    #pragma unroll
    for (int i = 0; i < 16; ++i) {
        const int qb = i * 256 + wid * 64;       // wave-uniform chunk base
        const int q  = qb + lane;
        const int r  = q >> 5;                   // col row 0..127
        const int kc = (q & 31) ^ (r & 7);       // inverse-swizzled source chunk
        gload_lds16(e + (size_t)(colBase + r) * D_EMB + kc * 8, &bufB[qb * 8]);
    }

    // ---- hoist ALL A fragments into registers (one burst, 32 loads) ----
    const bf16* aB = e + (size_t)(rowBase + wm * 64 + rr) * D_EMB + kh * 8;
    bf16x8 af[8][4];
    #pragma unroll
    for (int t = 0; t < 8; ++t)
        #pragma unroll
        for (int mi = 0; mi < 4; ++mi)
            af[t][mi] = *(const bf16x8*)(aB + (size_t)mi * 16 * D_EMB + t * 32);

    f32x4 acc[4][4];
    #pragma unroll
    for (int i = 0; i < 4; ++i)
        #pragma unroll
        for (int j = 0; j < 4; ++j) acc[i][j] = (f32x4){0.f, 0.f, 0.f, 0.f};

    __syncthreads();   // drains B staging (vmcnt) + labels; A-loads also drain

    // ---- barrier-free K loop: LDS B frags + register A frags ----
    #pragma unroll
    for (int t = 0; t < 8; ++t) {
        bf16x8 bg[4];
        #pragma unroll
        for (int ni = 0; ni < 4; ++ni) {
            const int colL = wn * 64 + ni * 16 + rr;
            const int kc = t * 4 + kh;
            bg[ni] = *(const bf16x8*)&bufB[(colL * 32 + (kc ^ (colL & 7))) * 8];
        }
        #pragma unroll
        for (int mi = 0; mi < 4; ++mi)
            #pragma unroll
            for (int ni = 0; ni < 4; ++ni)
                acc[mi][ni] = __builtin_amdgcn_mfma_f32_16x16x32_bf16(af[t][mi], bg[ni],
                                                                      acc[mi][ni], 0, 0, 0);
    }

    // ------------- fused epilogue: one exp per element, row + col partials
    const float s = *scale;
    int lc[4];
    #pragma unroll
    for (int ni = 0; ni < 4; ++ni) lc[ni] = labC[wn * 64 + ni * 16 + rr];
    float colA[4] = {0.f, 0.f, 0.f, 0.f}, colB[4] = {0.f, 0.f, 0.f, 0.f};

    #pragma unroll
    for (int mi = 0; mi < 4; ++mi) {
        #pragma unroll
        for (int r = 0; r < 4; ++r) {
            const int rowL = wm * 64 + mi * 16 + kh * 4 + r;
            const int lr = labR[rowL];
            float asum = 0.f, bsum = 0.f;
            #pragma unroll
            for (int ni = 0; ni < 4; ++ni) {
                const int colL = wn * 64 + ni * 16 + rr;
                const float val = acc[mi][ni][r] * s;
                const bool pos = (lr == lc[ni]);
                float ex = __expf(pos ? -val : val);
                if (diag && rowL == colL) ex = 0.f;   // exclude self-pairs
                if (pos) { asum += ex; colA[ni] += ex; }
                else     { bsum += ex; colB[ni] += ex; }
            }
            asum = red16(asum);
            bsum = red16(bsum);
            if (rr == 0) { rowsc[wn][rowL][0] = asum; rowsc[wn][rowL][1] = bsum; }
        }
    }

    if (!diag) {   // col-side (transposed contribution via symmetry)
        #pragma unroll
        for (int ni = 0; ni < 4; ++ni) {
            float a = colA[ni], b = colB[ni];
            a += __shfl_xor(a, 16); a += __shfl_xor(a, 32);
            b += __shfl_xor(b, 16); b += __shfl_xor(b, 32);
            if (lane < 16) {
                colsc[wm][wn * 64 + ni * 16 + lane][0] = a;
                colsc[wm][wn * 64 + ni * 16 + lane][1] = b;
            }
        }
    }
    __syncthreads();

    if (tid < PAN) {
        const float ra = rowsc[0][tid][0] + rowsc[1][tid][0];
        const float rb = rowsc[0][tid][1] + rowsc[1][tid][1];
        wsAB[(size_t)bx * N_EMB + rowBase + tid] = packbf(ra, rb);
        if (!diag) {
            const float ca = colsc[0][tid][0] + colsc[1][tid][0];
            const float cb = colsc[0][tid][1] + colsc[1][tid][1];
            wsAB[(size_t)by * N_EMB + colBase + tid] = packbf(ca, cb);
        }
    }
}

// --------------------------------------------------- per-row + segment reduce
__global__ __launch_bounds__(256) void reduce_rows(const unsigned* __restrict__ wsAB,
                                                   const int* __restrict__ labels,
                                                   float* __restrict__ part) {
    __shared__ float A[NUM_LABELS], B[NUM_LABELS];
    __shared__ int C[NUM_LABELS];
    const int tid = threadIdx.x;
    if (tid < NUM_LABELS) { A[tid] = 0.f; B[tid] = 0.f; C[tid] = 0; }
    __syncthreads();
    const int row = blockIdx.x * 256 + tid;
    float a = 0.f, b = 0.f;
    #pragma unroll
    for (int p = 0; p < NPAN; ++p) {
        const unsigned u = wsAB[(size_t)p * N_EMB + row];
        a += __builtin_bit_cast(float, u << 16);
        b += __builtin_bit_cast(float, u & 0xFFFF0000u);
    }
    const int l = labels[row];
    atomicAdd(&A[l], a);
    atomicAdd(&B[l], b);
    atomicAdd(&C[l], 1);
    __syncthreads();
    if (tid < NUM_LABELS) {
        float* p = part + ((size_t)blockIdx.x * NUM_LABELS + tid) * 3;
        p[0] = A[tid]; p[1] = B[tid]; p[2] = (float)C[tid];
    }
}

// ----------------------------------------------------------------- finalize
__global__ __launch_bounds__(128) void finalize_kernel(const float* __restrict__ part,
                                                       float* __restrict__ out) {
    const int tid = threadIdx.x;   // label id
    float A = 0.f, B = 0.f, c = 0.f;
    #pragma unroll
    for (int blk = 0; blk < 32; ++blk) {
        const float* p = part + ((size_t)blk * NUM_LABELS + tid) * 3;
        A += p[0]; B += p[1]; c += p[2];
    }
    float v = (c >= 2.f) ? A * B : 0.f;
    #pragma unroll
    for (int off = 32; off >= 1; off >>= 1) v += __shfl_xor(v, off);
    __shared__ float w2[2];
    if ((tid & 63) == 0) w2[tid >> 6] = v;
    __syncthreads();
    if (tid == 0) out[0] = logf(1.0f + w2[0] + w2[1]);
}

// ------------------------------------------------------------------ launcher
extern "C" void kernel_launch(void* const* d_in, const int* in_sizes, int n_in,
                              void* d_out, int out_size, void* d_ws, size_t ws_size,
                              hipStream_t stream) {
    const float* emb    = (const float*)d_in[0];
    const int*   labels = (const int*)d_in[1];
    const float* scale  = (const float*)d_in[2];
    float* out = (float*)d_out;

    bf16*     e16  = (bf16*)d_ws;                                     // 4 MB
    unsigned* wsAB = (unsigned*)((char*)d_ws + (size_t)N_EMB * D_EMB * sizeof(bf16)); // 2 MB
    float*    part = (float*)((char*)wsAB + (size_t)NPAN * N_EMB * sizeof(unsigned)); // 48 KB

    normalize_kernel<<<N_EMB / 4, 256, 0, stream>>>(emb, e16);
    cosent_main<<<NTRI, 256, 0, stream>>>(e16, labels, scale, wsAB);
    reduce_rows<<<N_EMB / 256, 256, 0, stream>>>(wsAB, labels, part);
    finalize_kernel<<<1, 128, 0, stream>>>(part, out);
}